// Round 8
// baseline (2899.489 us; speedup 1.0000x reference)
//
#include <hip/hip_runtime.h>

#define N_USERS 100000
#define N_ITEMS 50000
#define NTOT    150000        // N_USERS + N_ITEMS
#define E       128
#define NNZ     4800000
#define BATCH   4096
#define TILE    16            // rows per fused block (4 grps of 4 rows)
#define BSH     10            // log2(rows per bucket)
#define BROWS   1024          // rows per bucket
#define NBK     147           // ceil(NTOT / BROWS)
#define SLOT    16            // write-combine entries per bucket
#define NSEG    37            // column segments (4096 nodes = 2 MB source window)
#define SEGSH   12
#define NGRP    37500         // NTOT/4 four-row groups
#define GPB     256           // groups per bucket
#define NKEY    (GPB * NSEG)  // 9472
#define SUBL    1875          // blocks per cohort (5 x 1875 x 16 rows = 150000)

// ---- load helpers ----
__device__ __forceinline__ int   ldnt_i(const int* p)   { return __builtin_nontemporal_load(p); }
__device__ __forceinline__ float ldnt_f(const float* p) { return __builtin_nontemporal_load(p); }

// ---------------------------------------------------------------------------
// Build 1: per-bucket edge counts via LDS histograms.
__global__ __launch_bounds__(1024) void bucket_count(const int* __restrict__ rowA,
                                                     const int* __restrict__ rowH,
                                                     int* __restrict__ cntA,
                                                     int* __restrict__ cntH) {
    __shared__ int c[2 * NBK];
    for (int i = threadIdx.x; i < 2 * NBK; i += 1024) c[i] = 0;
    __syncthreads();
    int i = blockIdx.x * 1024 + threadIdx.x;
    const int stride = gridDim.x * 1024;
    for (; i < NNZ; i += stride) {
        atomicAdd(&c[ldnt_i(rowA + i) >> BSH], 1);
        atomicAdd(&c[NBK + (ldnt_i(rowH + i) >> BSH)], 1);
    }
    __syncthreads();
    for (int j = threadIdx.x; j < 2 * NBK; j += 1024) {
        const int v = c[j];
        if (v) atomicAdd(j < NBK ? (cntA + j) : (cntH + (j - NBK)), v);
    }
}

// Build 2: tiny serial scans -> bucket bases + scatter cursors.
__global__ __launch_bounds__(64) void bucket_scan(const int* __restrict__ cntA,
                                                  const int* __restrict__ cntH,
                                                  int* __restrict__ baseA, int* __restrict__ baseH,
                                                  int* __restrict__ gcurA, int* __restrict__ gcurH) {
    const int t = threadIdx.x;
    if (t == 0) {
        int run = 0;
        for (int j = 0; j < NBK; ++j) { baseA[j] = run; gcurA[j] = run; run += cntA[j]; }
        baseA[NBK] = run;
    } else if (t == 1) {
        int run = 0;
        for (int j = 0; j < NBK; ++j) { baseH[j] = run; gcurH[j] = run; run += cntH[j]; }
        baseH[NBK] = run;
    }
}

// Build 3: write-combining bucket scatter (stages (rl10<<18|col, val) by bucket).
__global__ __launch_bounds__(1024) void wc_scatter(const int* __restrict__ rowA, const int* __restrict__ colA,
                                                   const float* __restrict__ valA,
                                                   const int* __restrict__ rowH, const int* __restrict__ colH,
                                                   const float* __restrict__ valH,
                                                   int* __restrict__ gcurA, int* __restrict__ gcurH,
                                                   int2* __restrict__ stA, int2* __restrict__ stH) {
    __shared__ int  lcnt[2 * NBK];
    __shared__ int2 lent[2 * NBK * SLOT];
    for (int i = threadIdx.x; i < 2 * NBK; i += 1024) lcnt[i] = 0;
    __syncthreads();
    const int stride = gridDim.x * 1024;
    const int rounds = (NNZ + stride - 1) / stride;
    for (int rd = 0; rd < rounds; ++rd) {
        const int i = rd * stride + blockIdx.x * 1024 + threadIdx.x;
        if (i < NNZ) {
            {
                const int r = ldnt_i(rowA + i), cc = ldnt_i(colA + i);
                const float v = ldnt_f(valA + i);
                const int b = r >> BSH;
                const int2 pk = make_int2(((r & (BROWS - 1)) << 18) | cc, __float_as_int(v));
                const int n = atomicAdd(&lcnt[b], 1);
                if (n < SLOT) lent[b * SLOT + n] = pk;
                else          stA[atomicAdd(&gcurA[b], 1)] = pk;
            }
            {
                const int r = ldnt_i(rowH + i), cc = ldnt_i(colH + i);
                const float v = ldnt_f(valH + i);
                const int b = r >> BSH;
                const int gb = NBK + b;
                const int2 pk = make_int2(((r & (BROWS - 1)) << 18) | cc, __float_as_int(v));
                const int n = atomicAdd(&lcnt[gb], 1);
                if (n < SLOT) lent[gb * SLOT + n] = pk;
                else          stH[atomicAdd(&gcurH[b], 1)] = pk;
            }
        }
        __syncthreads();
        const int thresh = (rd == rounds - 1) ? 1 : 8;
        for (int gb = threadIdx.x; gb < 2 * NBK; gb += 1024) {
            int n = lcnt[gb]; if (n > SLOT) n = SLOT;
            if (n >= thresh) {
                int*  gc = (gb < NBK) ? &gcurA[gb] : &gcurH[gb - NBK];
                int2* st = (gb < NBK) ? stA : stH;
                const int p = atomicAdd(gc, n);
                for (int j = 0; j < n; ++j) st[p + j] = lent[gb * SLOT + j];
                lcnt[gb] = 0;
            }
        }
        __syncthreads();
    }
}

// Build 4: per-bucket (grp, seg)-sorted edge list + grp bases (monotone; spans
// are gbase[g]..gbase[g+1]). Edge record: bits18-19 = row-in-grp, 0-17 = col.
__global__ __launch_bounds__(1024) void bucket_csr_seg(
    const int2* __restrict__ stA, const int2* __restrict__ stH,
    const int* __restrict__ baseA, const int* __restrict__ baseH,
    int* __restrict__ gbaseA, int* __restrict__ gbaseH,
    int2* __restrict__ edA, int2* __restrict__ edH) {
    const int isH = blockIdx.x >= NBK;
    const int b   = isH ? blockIdx.x - NBK : blockIdx.x;
    const int2* st   = isH ? stH   : stA;
    const int*  base = isH ? baseH : baseA;
    int*  gbase = isH ? gbaseH : gbaseA;
    int2* ed = isH ? edH : edA;
    const int s = base[b], e = base[b + 1];
    const int t = threadIdx.x, lane = t & 63, wv = t >> 6;
    __shared__ int cnt[NKEY + 1];
    __shared__ int wsum[16], woff[16];
    __shared__ int carry, chtot;
    for (int i = t; i <= NKEY; i += 1024) cnt[i] = 0;
    if (t == 0) carry = 0;
    __syncthreads();
    for (int i = s + t; i < e; i += 1024) {
        const int pk = st[i].x;
        const int key = (pk >> 20) * NSEG + ((pk & 0x3FFFF) >> SEGSH);  // grp-in-bucket * 37 + seg
        atomicAdd(&cnt[key], 1);
    }
    __syncthreads();
    // exclusive scan of cnt[0..NKEY)
    for (int b2 = 0; b2 < NKEY; b2 += 1024) {
        const int idx = b2 + t;
        const int v = (idx < NKEY) ? cnt[idx] : 0;
        int x = v;
        #pragma unroll
        for (int off = 1; off < 64; off <<= 1) {
            const int n = __shfl_up(x, off);
            if (lane >= off) x += n;
        }
        if (lane == 63) wsum[wv] = x;
        __syncthreads();
        if (t == 0) { int a = 0; for (int w = 0; w < 16; ++w) { woff[w] = a; a += wsum[w]; } chtot = a; }
        __syncthreads();
        if (idx < NKEY) cnt[idx] = carry + woff[wv] + (x - v);
        __syncthreads();
        if (t == 0) carry += chtot;
        __syncthreads();
    }
    if (t == 0) cnt[NKEY] = e - s;
    __syncthreads();
    // grp bases (before cnt is consumed as cursor)
    if (t < GPB) {
        const int g = b * GPB + t;
        if (g < NGRP) gbase[g] = s + cnt[t * NSEG];
    }
    if (b == 0 && t == 0) gbase[NGRP] = NNZ;
    __syncthreads();
    // scatter into (grp, seg) order
    for (int i = s + t; i < e; i += 1024) {
        const int2 pk = st[i];
        const int key = (pk.x >> 20) * NSEG + ((pk.x & 0x3FFFF) >> SEGSH);
        const int p = s + atomicAdd(&cnt[key], 1);
        ed[p] = make_int2((((pk.x >> 18) & 3) << 18) | (pk.x & 0x3FFFF), pk.y);
    }
}

// generic int copy (metadata relocation before the FINAL layer)
__global__ __launch_bounds__(256) void copy_int(const int* __restrict__ src,
                                                int* __restrict__ dst, int n) {
    const int i = blockIdx.x * blockDim.x + threadIdx.x;
    if (i < n) dst[i] = src[i];
}

// ---------------------------------------------------------------------------
template<bool FIRST>
__device__ __forceinline__ float2 ldrow2(int c, const float* __restrict__ ue,
                                         const float* __restrict__ ie,
                                         const float* __restrict__ A, int lane) {
    const float* base;
    if constexpr (FIRST)
        base = (c < N_USERS) ? (ue + (size_t)c * E) : (ie + (size_t)(c - N_USERS) * E);
    else
        base = A + (size_t)c * E;
    return ((const float2*)base)[lane];
}

// rl is wave-uniform (broadcast edge record) -> uniform branch, no divergence
#define ACC4(ee, xv)                                                          \
    do {                                                                      \
        const int   rl_ = (ee).x >> 18;                                       \
        const float v_  = __int_as_float((ee).y);                             \
        if      (rl_ == 0) { p0.x = fmaf(v_, (xv).x, p0.x); p0.y = fmaf(v_, (xv).y, p0.y); } \
        else if (rl_ == 1) { p1.x = fmaf(v_, (xv).x, p1.x); p1.y = fmaf(v_, (xv).y, p1.y); } \
        else if (rl_ == 2) { p2.x = fmaf(v_, (xv).x, p2.x); p2.y = fmaf(v_, (xv).y, p2.y); } \
        else               { p3.x = fmaf(v_, (xv).x, p3.x); p3.y = fmaf(v_, (xv).y, p3.y); } \
    } while (0)

// Linear sweep of one grp's span (seg-sorted order), 4-deep gather pipeline,
// 4-row register accumulators.
template<bool FIRST>
__device__ __forceinline__ void grp_sweep(int s, int e, const int2* __restrict__ ed,
                                          const float* __restrict__ ue,
                                          const float* __restrict__ ie,
                                          const float* __restrict__ A, int lane,
                                          float2& p0, float2& p1, float2& p2, float2& p3) {
    int i = s;
    for (; i + 3 < e; i += 4) {
        const int2 e0 = ed[i], e1 = ed[i + 1], e2 = ed[i + 2], e3 = ed[i + 3];
        const float2 x0 = ldrow2<FIRST>(e0.x & 0x3FFFF, ue, ie, A, lane);
        const float2 x1 = ldrow2<FIRST>(e1.x & 0x3FFFF, ue, ie, A, lane);
        const float2 x2 = ldrow2<FIRST>(e2.x & 0x3FFFF, ue, ie, A, lane);
        const float2 x3 = ldrow2<FIRST>(e3.x & 0x3FFFF, ue, ie, A, lane);
        ACC4(e0, x0); ACC4(e1, x1); ACC4(e2, x2); ACC4(e3, x3);
    }
    for (; i < e; ++i) {
        const int2 e0 = ed[i];
        const float2 x0 = ldrow2<FIRST>(e0.x & 0x3FFFF, ue, ie, A, lane);
        ACC4(e0, x0);
    }
}

// Fused layer: wave sweeps one grp (4 rows) per adjacency -> LDS -> Linear.
// Cohort launches (grid=SUBL) keep co-resident blocks seg-aligned.
template<bool FIRST>
__global__ __launch_bounds__(256) void fused_grp(
    const float* __restrict__ A,
    const float* __restrict__ ue, const float* __restrict__ ie,
    const int* __restrict__ gbaseA, const int2* __restrict__ edA,
    const int* __restrict__ gbaseH, const int2* __restrict__ edH,
    const float* __restrict__ Wk, const float* __restrict__ bk,
    int row0, float* __restrict__ out) {
    __shared__ float sP[TILE][E];
    __shared__ float sD[TILE][E];
    const int t = threadIdx.x, lane = t & 63, wv = t >> 6;
    const int g = (row0 >> 2) + blockIdx.x * 4 + wv;
    {
        float2 p0{0,0}, p1{0,0}, p2{0,0}, p3{0,0};
        grp_sweep<FIRST>(gbaseA[g], gbaseA[g + 1], edA, ue, ie, A, lane, p0, p1, p2, p3);
        ((float2*)&sP[wv * 4 + 0][0])[lane] = p0;
        ((float2*)&sP[wv * 4 + 1][0])[lane] = p1;
        ((float2*)&sP[wv * 4 + 2][0])[lane] = p2;
        ((float2*)&sP[wv * 4 + 3][0])[lane] = p3;
    }
    {
        float2 p0{0,0}, p1{0,0}, p2{0,0}, p3{0,0};
        grp_sweep<FIRST>(gbaseH[g], gbaseH[g + 1], edH, ue, ie, A, lane, p0, p1, p2, p3);
        ((float2*)&sD[wv * 4 + 0][0])[lane] = p0;
        ((float2*)&sD[wv * 4 + 1][0])[lane] = p1;
        ((float2*)&sD[wv * 4 + 2][0])[lane] = p2;
        ((float2*)&sD[wv * 4 + 3][0])[lane] = p3;
    }
    __syncthreads();

    // ---- phase 2: [TILE,256] @ [256,128] + bias ----
    const int j = t & (E - 1);
    const int h = t >> 7;
    float acc[8];
    const float bj = bk[j];
    #pragma unroll
    for (int rr = 0; rr < 8; ++rr) acc[rr] = bj;
    #pragma unroll 4
    for (int i = 0; i < E; ++i) {
        const float w = Wk[(size_t)i * E + j];
        #pragma unroll
        for (int rr = 0; rr < 8; ++rr) acc[rr] = fmaf(sP[h * 8 + rr][i], w, acc[rr]);
    }
    #pragma unroll 4
    for (int i = 0; i < E; ++i) {
        const float w = Wk[(size_t)(E + i) * E + j];
        #pragma unroll
        for (int rr = 0; rr < 8; ++rr) acc[rr] = fmaf(sD[h * 8 + rr][i], w, acc[rr]);
    }
    #pragma unroll
    for (int rr = 0; rr < 8; ++rr)
        out[(size_t)(row0 + blockIdx.x * TILE + h * 8 + rr) * E + j] = acc[rr];
}

// FINAL layer: 8192 requested rows. Per slot, sweep its grp span but gather
// ONLY target-row edges (wave-uniform branch skips the other ~75%).
__global__ __launch_bounds__(256) void fused_final(
    const float* __restrict__ A,
    const int* __restrict__ gbaseA, const int2* __restrict__ edA,
    const int* __restrict__ gbaseH, const int2* __restrict__ edH,
    const float* __restrict__ Wk, const float* __restrict__ bk,
    const int* __restrict__ users, const int* __restrict__ items,
    float* __restrict__ out) {
    __shared__ float sP[TILE][E];
    __shared__ float sD[TILE][E];
    const int t = threadIdx.x, lane = t & 63, wv = t >> 6;

    #pragma unroll
    for (int q = 0; q < 4; ++q) {
        const int slot = blockIdx.x * TILE + wv * 4 + q;
        const int r = (slot < BATCH) ? users[slot] : (N_USERS + items[slot - BATCH]);
        const int g = r >> 2, tgt = (r & 3) << 18;
        float2 ap{0,0};
        for (int i = gbaseA[g], e = gbaseA[g + 1]; i < e; ++i) {
            const int2 ee = edA[i];
            if ((ee.x & 0xC0000) == tgt) {
                const float2 xv = ((const float2*)(A + (size_t)(ee.x & 0x3FFFF) * E))[lane];
                const float v = __int_as_float(ee.y);
                ap.x = fmaf(v, xv.x, ap.x); ap.y = fmaf(v, xv.y, ap.y);
            }
        }
        ((float2*)&sP[wv * 4 + q][0])[lane] = ap;
        float2 ad{0,0};
        for (int i = gbaseH[g], e = gbaseH[g + 1]; i < e; ++i) {
            const int2 ee = edH[i];
            if ((ee.x & 0xC0000) == tgt) {
                const float2 xv = ((const float2*)(A + (size_t)(ee.x & 0x3FFFF) * E))[lane];
                const float v = __int_as_float(ee.y);
                ad.x = fmaf(v, xv.x, ad.x); ad.y = fmaf(v, xv.y, ad.y);
            }
        }
        ((float2*)&sD[wv * 4 + q][0])[lane] = ad;
    }
    __syncthreads();

    const int j = t & (E - 1);
    const int h = t >> 7;
    float acc[8];
    const float bj = bk[j];
    #pragma unroll
    for (int rr = 0; rr < 8; ++rr) acc[rr] = bj;
    #pragma unroll 4
    for (int i = 0; i < E; ++i) {
        const float w = Wk[(size_t)i * E + j];
        #pragma unroll
        for (int rr = 0; rr < 8; ++rr) acc[rr] = fmaf(sP[h * 8 + rr][i], w, acc[rr]);
    }
    #pragma unroll 4
    for (int i = 0; i < E; ++i) {
        const float w = Wk[(size_t)(E + i) * E + j];
        #pragma unroll
        for (int rr = 0; rr < 8; ++rr) acc[rr] = fmaf(sD[h * 8 + rr][i], w, acc[rr]);
    }
    #pragma unroll
    for (int rr = 0; rr < 8; ++rr)
        out[(size_t)(blockIdx.x * TILE + h * 8 + rr) * E + j] = acc[rr];
}

// ---------------------------------------------------------------------------
extern "C" void kernel_launch(void* const* d_in, const int* in_sizes, int n_in,
                              void* d_out, int out_size, void* d_ws, size_t ws_size,
                              hipStream_t stream) {
    const float* user_emb = (const float*)d_in[0];
    const float* item_emb = (const float*)d_in[1];
    const float* adj_val  = (const float*)d_in[2];
    const float* hp_val   = (const float*)d_in[3];
    const float* W        = (const float*)d_in[4];
    const float* bias     = (const float*)d_in[5];
    const int*   adj_row  = (const int*)d_in[6];
    const int*   adj_col  = (const int*)d_in[7];
    const int*   hp_row   = (const int*)d_in[8];
    const int*   hp_col   = (const int*)d_in[9];
    const int*   users    = (const int*)d_in[10];
    const int*   items    = (const int*)d_in[11];
    float* out = (float*)d_out;

    // ---- workspace: exactly 230,400,000 B (proven available) ----
    float* buf0 = (float*)d_ws;                       // ego ping / build staging
    float* buf1 = buf0 + (size_t)NTOT * E;            // ego pong / FINAL metadata
    int2*  edA  = (int2*)(buf1 + (size_t)NTOT * E);   // (grp,seg)-sorted edges A
    int2*  edH  = edA + NNZ;                          // (grp,seg)-sorted edges H
    int2*  stA  = (int2*)buf0;                        // staging aliases buf0
    int2*  stH  = stA + NNZ;

    // ---- metadata in d_out (4.19 MB; fully overwritten by FINAL) ----
    int* gbA_d = (int*)d_out;                         // NGRP+1
    int* gbH_d = gbA_d + (NGRP + 1);                  // NGRP+1
    int* cntA  = gbH_d + (NGRP + 1);
    int* cntH  = cntA + NBK;
    int* baseA = cntH + NBK;
    int* baseH = baseA + (NBK + 1);
    int* gcurA = baseH + (NBK + 1);
    int* gcurH = gcurA + NBK;
    const int META_INTS = 2 * (NGRP + 1);             // 75002

    // FINAL-time metadata copies live in buf1 (dead during FINAL)
    int* gbA_f = (int*)buf1;
    int* gbH_f = gbA_f + (NGRP + 1);

    // ---- build (grp,seg)-sorted edge lists (once; reused across layers) ----
    hipMemsetAsync(cntA, 0, (size_t)2 * NBK * sizeof(int), stream);
    bucket_count<<<256, 1024, 0, stream>>>(adj_row, hp_row, cntA, cntH);
    bucket_scan<<<1, 64, 0, stream>>>(cntA, cntH, baseA, baseH, gcurA, gcurH);
    wc_scatter<<<256, 1024, 0, stream>>>(adj_row, adj_col, adj_val,
                                         hp_row, hp_col, hp_val,
                                         gcurA, gcurH, stA, stH);
    bucket_csr_seg<<<2 * NBK, 1024, 0, stream>>>(stA, stH, baseA, baseH,
                                                 gbA_d, gbH_d, edA, edH);

    // ---- layers 0 and 1: 5 resident cohorts each (soft seg lockstep) ----
    for (int s5 = 0; s5 < 5; ++s5)
        fused_grp<true><<<SUBL, 256, 0, stream>>>(
            nullptr, user_emb, item_emb, gbA_d, edA, gbH_d, edH,
            W, bias, s5 * SUBL * TILE, buf1);
    for (int s5 = 0; s5 < 5; ++s5)
        fused_grp<false><<<SUBL, 256, 0, stream>>>(
            buf1, nullptr, nullptr, gbA_d, edA, gbH_d, edH,
            W + (size_t)2 * E * E, bias + E, s5 * SUBL * TILE, buf0);

    // relocate metadata out of d_out, then FINAL overwrites d_out
    copy_int<<<(META_INTS + 255) / 256, 256, 0, stream>>>(gbA_d, gbA_f, META_INTS);
    fused_final<<<(2 * BATCH) / TILE, 256, 0, stream>>>(
        buf0, gbA_f, edA, gbH_f, edH,
        W + (size_t)4 * E * E, bias + 2 * E, users, items, out);
}

// Round 9
// 2049.998 us; speedup vs baseline: 1.4144x; 1.4144x over previous
//
#include <hip/hip_runtime.h>

#define N_USERS 100000
#define N_ITEMS 50000
#define NTOT    150000        // N_USERS + N_ITEMS
#define E       128
#define NNZ     4800000
#define BATCH   4096
#define TILE    16            // rows per fused block (150000 = 16*9375, 8192 = 16*512)
#define BSH     10            // log2(rows per bucket)
#define BROWS   1024          // rows per bucket
#define NBK     147           // ceil(NTOT / BROWS)
#define SLOT    16            // write-combine entries per bucket

typedef int v4i __attribute__((ext_vector_type(4)));

// ---- load helpers ----
__device__ __forceinline__ int   ldnt_i(const int* p)   { return __builtin_nontemporal_load(p); }
__device__ __forceinline__ float ldnt_f(const float* p) { return __builtin_nontemporal_load(p); }
__device__ __forceinline__ v4i   ld_v4(const void* p)   { return *(const v4i*)p; }

// ---------------------------------------------------------------------------
// Build 1: per-bucket edge counts via LDS histograms.
__global__ __launch_bounds__(1024) void bucket_count(const int* __restrict__ rowA,
                                                     const int* __restrict__ rowH,
                                                     int* __restrict__ cntA,
                                                     int* __restrict__ cntH) {
    __shared__ int c[2 * NBK];
    for (int i = threadIdx.x; i < 2 * NBK; i += 1024) c[i] = 0;
    __syncthreads();
    int i = blockIdx.x * 1024 + threadIdx.x;
    const int stride = gridDim.x * 1024;
    for (; i < NNZ; i += stride) {
        atomicAdd(&c[ldnt_i(rowA + i) >> BSH], 1);
        atomicAdd(&c[NBK + (ldnt_i(rowH + i) >> BSH)], 1);
    }
    __syncthreads();
    for (int j = threadIdx.x; j < 2 * NBK; j += 1024) {
        const int v = c[j];
        if (v) atomicAdd(j < NBK ? (cntA + j) : (cntH + (j - NBK)), v);
    }
}

// Build 2: tiny serial scans -> bucket bases + scatter cursors.
__global__ __launch_bounds__(64) void bucket_scan(const int* __restrict__ cntA,
                                                  const int* __restrict__ cntH,
                                                  int* __restrict__ baseA, int* __restrict__ baseH,
                                                  int* __restrict__ gcurA, int* __restrict__ gcurH) {
    const int t = threadIdx.x;
    if (t == 0) {
        int run = 0;
        for (int j = 0; j < NBK; ++j) { baseA[j] = run; gcurA[j] = run; run += cntA[j]; }
        baseA[NBK] = run;
    } else if (t == 1) {
        int run = 0;
        for (int j = 0; j < NBK; ++j) { baseH[j] = run; gcurH[j] = run; run += cntH[j]; }
        baseH[NBK] = run;
    }
}

// Build 3: write-combining bucket scatter (stages (rl10<<18|col, val) by bucket).
__global__ __launch_bounds__(1024) void wc_scatter(const int* __restrict__ rowA, const int* __restrict__ colA,
                                                   const float* __restrict__ valA,
                                                   const int* __restrict__ rowH, const int* __restrict__ colH,
                                                   const float* __restrict__ valH,
                                                   int* __restrict__ gcurA, int* __restrict__ gcurH,
                                                   int2* __restrict__ stA, int2* __restrict__ stH) {
    __shared__ int  lcnt[2 * NBK];
    __shared__ int2 lent[2 * NBK * SLOT];
    for (int i = threadIdx.x; i < 2 * NBK; i += 1024) lcnt[i] = 0;
    __syncthreads();
    const int stride = gridDim.x * 1024;
    const int rounds = (NNZ + stride - 1) / stride;
    for (int rd = 0; rd < rounds; ++rd) {
        const int i = rd * stride + blockIdx.x * 1024 + threadIdx.x;
        if (i < NNZ) {
            {
                const int r = ldnt_i(rowA + i), cc = ldnt_i(colA + i);
                const float v = ldnt_f(valA + i);
                const int b = r >> BSH;
                const int2 pk = make_int2(((r & (BROWS - 1)) << 18) | cc, __float_as_int(v));
                const int n = atomicAdd(&lcnt[b], 1);
                if (n < SLOT) lent[b * SLOT + n] = pk;
                else          stA[atomicAdd(&gcurA[b], 1)] = pk;
            }
            {
                const int r = ldnt_i(rowH + i), cc = ldnt_i(colH + i);
                const float v = ldnt_f(valH + i);
                const int b = r >> BSH;
                const int gb = NBK + b;
                const int2 pk = make_int2(((r & (BROWS - 1)) << 18) | cc, __float_as_int(v));
                const int n = atomicAdd(&lcnt[gb], 1);
                if (n < SLOT) lent[gb * SLOT + n] = pk;
                else          stH[atomicAdd(&gcurH[b], 1)] = pk;
            }
        }
        __syncthreads();
        const int thresh = (rd == rounds - 1) ? 1 : 8;
        for (int gb = threadIdx.x; gb < 2 * NBK; gb += 1024) {
            int n = lcnt[gb]; if (n > SLOT) n = SLOT;
            if (n >= thresh) {
                int*  gc = (gb < NBK) ? &gcurA[gb] : &gcurH[gb - NBK];
                int2* st = (gb < NBK) ? stA : stH;
                const int p = atomicAdd(gc, n);
                for (int j = 0; j < n; ++j) st[p + j] = lent[gb * SLOT + j];
                lcnt[gb] = 0;
            }
        }
        __syncthreads();
    }
}

// Build 4: per-bucket exact CSR + rowptr. Records carry COL ONLY (masked).
__global__ __launch_bounds__(1024) void bucket_csr(const int2* __restrict__ stA, const int2* __restrict__ stH,
                                                   const int* __restrict__ baseA, const int* __restrict__ baseH,
                                                   int* __restrict__ rpA, int* __restrict__ rpH,
                                                   int2* __restrict__ edA, int2* __restrict__ edH) {
    const int isH = blockIdx.x >= NBK;
    const int b   = isH ? blockIdx.x - NBK : blockIdx.x;
    const int2* st   = isH ? stH   : stA;
    const int*  base = isH ? baseH : baseA;
    int*  rp = isH ? rpH : rpA;
    int2* ed = isH ? edH : edA;
    const int s = base[b], e = base[b + 1];
    const int t = threadIdx.x, lane = t & 63, wv = t >> 6;
    __shared__ int cnt[BROWS];
    __shared__ int wsum[16], woff[16];
    cnt[t] = 0;
    __syncthreads();
    for (int i = s + t; i < e; i += 1024) atomicAdd(&cnt[st[i].x >> 18], 1);
    __syncthreads();
    const int v = cnt[t];
    int x = v;
    #pragma unroll
    for (int off = 1; off < 64; off <<= 1) {
        const int n = __shfl_up(x, off);
        if (lane >= off) x += n;
    }
    if (lane == 63) wsum[wv] = x;
    __syncthreads();
    if (t == 0) { int acc = 0; for (int w = 0; w < 16; ++w) { woff[w] = acc; acc += wsum[w]; } }
    __syncthreads();
    const int excl = woff[wv] + (x - v);
    const int rglob = (b << BSH) + t;
    if (rglob < NTOT) rp[rglob] = s + excl;
    __syncthreads();
    cnt[t] = excl;
    __syncthreads();
    for (int i = s + t; i < e; i += 1024) {
        const int2 pk = st[i];
        const int rl = pk.x >> 18;
        const int p = s + atomicAdd(&cnt[rl], 1);
        ed[p] = make_int2(pk.x & 0x3FFFF, pk.y);   // col only
    }
    if (t == 0 && b == 0) rp[NTOT] = NNZ;
}

// generic int copy (rowptr relocation before the FINAL layer)
__global__ __launch_bounds__(256) void copy_int(const int* __restrict__ src,
                                                int* __restrict__ dst, int n) {
    const int i = blockIdx.x * blockDim.x + threadIdx.x;
    if (i < n) dst[i] = src[i];
}

// ---------------------------------------------------------------------------
// Row base pointer (float). Layer 0 reads straight from the input embeddings.
template<bool FIRST>
__device__ __forceinline__ const float* rowb(int c, const float* __restrict__ ue,
                                             const float* __restrict__ ie,
                                             const float* __restrict__ A) {
    if constexpr (FIRST)
        return (c < N_USERS) ? (ue + (size_t)c * E) : (ie + (size_t)(c - N_USERS) * E);
    else
        return A + (size_t)c * E;
}

// ---- half-column pair-gather: lanes 0-31 = even edge, 32-63 = odd edge,
// each lane holds a float2 slice of the 64-float half-row. ----
template<bool FIRST, int HALF>
__device__ __forceinline__ void pf_half(v4i q, const float* __restrict__ ue,
                                        const float* __restrict__ ie,
                                        const float* __restrict__ A,
                                        int sub, int half, float2& acc) {
    const int   c = half ? q[2] : q[0];
    const float v = __int_as_float(half ? q[3] : q[1]);
    const float2 xv = ((const float2*)(rowb<FIRST>(c, ue, ie, A) + HALF * 64))[sub];
    acc.x = fmaf(v, xv.x, acc.x);
    acc.y = fmaf(v, xv.y, acc.y);
}

template<bool FIRST, int HALF>
__device__ __forceinline__ float2 accum_half(int s, int e, const int2* __restrict__ ed,
                                             const float* __restrict__ ue,
                                             const float* __restrict__ ie,
                                             const float* __restrict__ A,
                                             int sub, int half) {
    float2 a{0.f, 0.f}, b{0.f, 0.f};
    int i = s;
    if (i < e && (i & 1)) {                 // leading edge to even-align pairs
        const int2 t0 = ed[i];
        const float v = half ? 0.f : __int_as_float(t0.y);
        const float2 xv = ((const float2*)(rowb<FIRST>(t0.x, ue, ie, A) + HALF * 64))[sub];
        a.x = fmaf(v, xv.x, a.x); a.y = fmaf(v, xv.y, a.y);
        ++i;
    }
    for (; i + 7 < e; i += 8) {             // 4 pairs = 8 edges
        const v4i q0 = ld_v4(ed + i);
        const v4i q1 = ld_v4(ed + i + 2);
        const v4i q2 = ld_v4(ed + i + 4);
        const v4i q3 = ld_v4(ed + i + 6);
        pf_half<FIRST, HALF>(q0, ue, ie, A, sub, half, a);
        pf_half<FIRST, HALF>(q1, ue, ie, A, sub, half, b);
        pf_half<FIRST, HALF>(q2, ue, ie, A, sub, half, a);
        pf_half<FIRST, HALF>(q3, ue, ie, A, sub, half, b);
    }
    for (; i + 1 < e; i += 2) {
        const v4i q = ld_v4(ed + i);
        pf_half<FIRST, HALF>(q, ue, ie, A, sub, half, a);
    }
    if (i < e) {                            // trailing single edge
        const int2 t0 = ed[i];
        const float v = half ? 0.f : __int_as_float(t0.y);
        const float2 xv = ((const float2*)(rowb<FIRST>(t0.x, ue, ie, A) + HALF * 64))[sub];
        a.x = fmaf(v, xv.x, a.x); a.y = fmaf(v, xv.y, a.y);
    }
    return make_float2(a.x + b.x, a.y + b.y);
}

// ---------------------------------------------------------------------------
// Pass A (HALF=0 source columns): pos/dis half-rows -> outb as scratch.
//   outb[r][0:64] = pos_half, outb[r][64:128] = dis_half. No LDS, no Linear.
template<bool FIRST>
__global__ __launch_bounds__(256) void fused_passA(
    const float* __restrict__ A,
    const float* __restrict__ ue, const float* __restrict__ ie,
    const int* __restrict__ rpA, const int2* __restrict__ edA,
    const int* __restrict__ rpH, const int2* __restrict__ edH,
    float* __restrict__ outb) {
    const int t = threadIdx.x, lane = t & 63, sub = lane & 31, half = lane >> 5, wv = t >> 6;
    const int r0 = blockIdx.x * TILE;
    #pragma unroll
    for (int rl = 0; rl < 4; ++rl) {
        const int r = r0 + wv * 4 + rl;
        const float2 ap = accum_half<FIRST, 0>(rpA[r], rpA[r + 1], edA, ue, ie, A, sub, half);
        const float2 ad = accum_half<FIRST, 0>(rpH[r], rpH[r + 1], edH, ue, ie, A, sub, half);
        float2 send = half ? ap : ad;
        float2 recv;
        recv.x = __shfl_xor(send.x, 32);
        recv.y = __shfl_xor(send.y, 32);
        if (!half) {
            const float2 f{ap.x + recv.x, ap.y + recv.y};
            ((float2*)(outb + (size_t)r * E))[sub] = f;          // pos half -> cols 0-63
        } else {
            const float2 f{ad.x + recv.x, ad.y + recv.y};
            ((float2*)(outb + (size_t)r * E + 64))[sub] = f;     // dis half -> cols 64-127
        }
    }
}

// Pass B (HALF=1 source columns): other halves in regs + scratch reload ->
// full pos/dis in LDS -> Linear -> overwrite outb rows with the layer output.
template<bool FIRST>
__global__ __launch_bounds__(256) void fused_passB(
    const float* __restrict__ A,
    const float* __restrict__ ue, const float* __restrict__ ie,
    const int* __restrict__ rpA, const int2* __restrict__ edA,
    const int* __restrict__ rpH, const int2* __restrict__ edH,
    const float* __restrict__ Wk, const float* __restrict__ bk,
    float* __restrict__ outb) {
    __shared__ float sP[TILE][E];
    __shared__ float sD[TILE][E];
    const int t = threadIdx.x, lane = t & 63, sub = lane & 31, half = lane >> 5, wv = t >> 6;
    const int r0 = blockIdx.x * TILE;
    #pragma unroll
    for (int rl = 0; rl < 4; ++rl) {
        const int r = r0 + wv * 4 + rl;
        const float2 ap = accum_half<FIRST, 1>(rpA[r], rpA[r + 1], edA, ue, ie, A, sub, half);
        const float2 ad = accum_half<FIRST, 1>(rpH[r], rpH[r + 1], edH, ue, ie, A, sub, half);
        float2 send = half ? ap : ad;
        float2 recv;
        recv.x = __shfl_xor(send.x, 32);
        recv.y = __shfl_xor(send.y, 32);
        if (!half) {
            const float2 f{ap.x + recv.x, ap.y + recv.y};
            ((float2*)&sP[wv * 4 + rl][64])[sub] = f;            // pos cols 64-127
        } else {
            const float2 f{ad.x + recv.x, ad.y + recv.y};
            ((float2*)&sD[wv * 4 + rl][64])[sub] = f;            // dis cols 64-127
        }
    }
    // reload pass-A scratch: 16 rows x 64 floats each for pos and dis
    {
        const int row = t >> 4;           // 0..15
        const int q   = t & 15;           // 16 x float4 = 64 floats
        const float4 vp = *(const float4*)(outb + (size_t)(r0 + row) * E + q * 4);
        const float4 vd = *(const float4*)(outb + (size_t)(r0 + row) * E + 64 + q * 4);
        *(float4*)&sP[row][q * 4] = vp;
        *(float4*)&sD[row][q * 4] = vd;
    }
    __syncthreads();

    // ---- Linear: [TILE,256] @ [256,128] + bias ----
    const int j = t & (E - 1);
    const int h = t >> 7;
    float acc[8];
    const float bj = bk[j];
    #pragma unroll
    for (int rr = 0; rr < 8; ++rr) acc[rr] = bj;
    #pragma unroll 4
    for (int i = 0; i < E; ++i) {
        const float w = Wk[(size_t)i * E + j];
        #pragma unroll
        for (int rr = 0; rr < 8; ++rr) acc[rr] = fmaf(sP[h * 8 + rr][i], w, acc[rr]);
    }
    #pragma unroll 4
    for (int i = 0; i < E; ++i) {
        const float w = Wk[(size_t)(E + i) * E + j];
        #pragma unroll
        for (int rr = 0; rr < 8; ++rr) acc[rr] = fmaf(sD[h * 8 + rr][i], w, acc[rr]);
    }
    #pragma unroll
    for (int rr = 0; rr < 8; ++rr)
        outb[(size_t)(r0 + h * 8 + rr) * E + j] = acc[rr];
}

// ---------------------------------------------------------------------------
// FINAL layer: full-row pair-gather over per-row CSR spans for the 8192
// requested rows, then Linear, writing d_out. (Round-6 structure.)
__device__ __forceinline__ void pf_full(v4i q, const float* __restrict__ A,
                                        int sub, int half, float4& acc) {
    const int   c = half ? q[2] : q[0];
    const float v = __int_as_float(half ? q[3] : q[1]);
    const float4 xv = ((const float4*)(A + (size_t)c * E))[sub];
    acc.x = fmaf(v, xv.x, acc.x);
    acc.y = fmaf(v, xv.y, acc.y);
    acc.z = fmaf(v, xv.z, acc.z);
    acc.w = fmaf(v, xv.w, acc.w);
}

__device__ __forceinline__ float4 accum_full(int s, int e, const int2* __restrict__ ed,
                                             const float* __restrict__ A, int sub, int half) {
    float4 a{0.f,0.f,0.f,0.f}, b{0.f,0.f,0.f,0.f};
    int i = s;
    if (i < e && (i & 1)) {
        const int2 t0 = ed[i];
        const float v = half ? 0.f : __int_as_float(t0.y);
        const float4 xv = ((const float4*)(A + (size_t)t0.x * E))[sub];
        a.x = fmaf(v, xv.x, a.x); a.y = fmaf(v, xv.y, a.y);
        a.z = fmaf(v, xv.z, a.z); a.w = fmaf(v, xv.w, a.w);
        ++i;
    }
    for (; i + 7 < e; i += 8) {
        const v4i q0 = ld_v4(ed + i);
        const v4i q1 = ld_v4(ed + i + 2);
        const v4i q2 = ld_v4(ed + i + 4);
        const v4i q3 = ld_v4(ed + i + 6);
        pf_full(q0, A, sub, half, a);
        pf_full(q1, A, sub, half, b);
        pf_full(q2, A, sub, half, a);
        pf_full(q3, A, sub, half, b);
    }
    for (; i + 1 < e; i += 2) {
        const v4i q = ld_v4(ed + i);
        pf_full(q, A, sub, half, a);
    }
    if (i < e) {
        const int2 t0 = ed[i];
        const float v = half ? 0.f : __int_as_float(t0.y);
        const float4 xv = ((const float4*)(A + (size_t)t0.x * E))[sub];
        a.x = fmaf(v, xv.x, a.x); a.y = fmaf(v, xv.y, a.y);
        a.z = fmaf(v, xv.z, a.z); a.w = fmaf(v, xv.w, a.w);
    }
    return make_float4(a.x + b.x, a.y + b.y, a.z + b.z, a.w + b.w);
}

__global__ __launch_bounds__(256) void fused_final(
    const float* __restrict__ A,
    const int* __restrict__ rpA, const int2* __restrict__ edA,
    const int* __restrict__ rpH, const int2* __restrict__ edH,
    const float* __restrict__ Wk, const float* __restrict__ bk,
    const int* __restrict__ users, const int* __restrict__ items,
    float* __restrict__ out) {
    __shared__ float sP[TILE][E];
    __shared__ float sD[TILE][E];
    const int t = threadIdx.x, lane = t & 63, sub = lane & 31, half = lane >> 5, wv = t >> 6;

    #pragma unroll
    for (int rl = 0; rl < 4; ++rl) {
        const int slot = blockIdx.x * TILE + wv * 4 + rl;
        const int r = (slot < BATCH) ? users[slot] : (N_USERS + items[slot - BATCH]);
        const float4 ap = accum_full(rpA[r], rpA[r + 1], edA, A, sub, half);
        const float4 ad = accum_full(rpH[r], rpH[r + 1], edH, A, sub, half);
        float4 send = half ? ap : ad;
        float4 recv;
        recv.x = __shfl_xor(send.x, 32);
        recv.y = __shfl_xor(send.y, 32);
        recv.z = __shfl_xor(send.z, 32);
        recv.w = __shfl_xor(send.w, 32);
        if (!half) {
            ((float4*)&sP[wv * 4 + rl][0])[sub] = make_float4(ap.x + recv.x, ap.y + recv.y,
                                                              ap.z + recv.z, ap.w + recv.w);
        } else {
            ((float4*)&sD[wv * 4 + rl][0])[sub] = make_float4(ad.x + recv.x, ad.y + recv.y,
                                                              ad.z + recv.z, ad.w + recv.w);
        }
    }
    __syncthreads();

    const int j = t & (E - 1);
    const int h = t >> 7;
    float acc[8];
    const float bj = bk[j];
    #pragma unroll
    for (int rr = 0; rr < 8; ++rr) acc[rr] = bj;
    #pragma unroll 4
    for (int i = 0; i < E; ++i) {
        const float w = Wk[(size_t)i * E + j];
        #pragma unroll
        for (int rr = 0; rr < 8; ++rr) acc[rr] = fmaf(sP[h * 8 + rr][i], w, acc[rr]);
    }
    #pragma unroll 4
    for (int i = 0; i < E; ++i) {
        const float w = Wk[(size_t)(E + i) * E + j];
        #pragma unroll
        for (int rr = 0; rr < 8; ++rr) acc[rr] = fmaf(sD[h * 8 + rr][i], w, acc[rr]);
    }
    #pragma unroll
    for (int rr = 0; rr < 8; ++rr)
        out[(size_t)(blockIdx.x * TILE + h * 8 + rr) * E + j] = acc[rr];
}

// ---------------------------------------------------------------------------
extern "C" void kernel_launch(void* const* d_in, const int* in_sizes, int n_in,
                              void* d_out, int out_size, void* d_ws, size_t ws_size,
                              hipStream_t stream) {
    const float* user_emb = (const float*)d_in[0];
    const float* item_emb = (const float*)d_in[1];
    const float* adj_val  = (const float*)d_in[2];
    const float* hp_val   = (const float*)d_in[3];
    const float* W        = (const float*)d_in[4];
    const float* bias     = (const float*)d_in[5];
    const int*   adj_row  = (const int*)d_in[6];
    const int*   adj_col  = (const int*)d_in[7];
    const int*   hp_row   = (const int*)d_in[8];
    const int*   hp_col   = (const int*)d_in[9];
    const int*   users    = (const int*)d_in[10];
    const int*   items    = (const int*)d_in[11];
    float* out = (float*)d_out;

    // ---- workspace: exactly 230,400,000 B (proven available) ----
    float* buf0 = (float*)d_ws;                       // ego ping / build staging
    float* buf1 = buf0 + (size_t)NTOT * E;            // ego pong / final rowptrs
    int2*  edA  = (int2*)(buf1 + (size_t)NTOT * E);   // CSR edges A   38.4 MB
    int2*  edH  = edA + NNZ;                          // CSR edges H   38.4 MB
    int2*  stA  = (int2*)buf0;                        // staging aliases buf0
    int2*  stH  = stA + NNZ;

    // ---- metadata in d_out (4.19 MB; fully overwritten by FINAL) ----
    int* rpA   = (int*)d_out;                         // NTOT+1
    int* rpH   = rpA + (NTOT + 1);                    // NTOT+1
    int* cntA  = rpH + (NTOT + 1);
    int* cntH  = cntA + NBK;
    int* baseA = cntH + NBK;
    int* baseH = baseA + (NBK + 1);
    int* gcurA = baseH + (NBK + 1);
    int* gcurH = gcurA + NBK;

    // FINAL-time rowptr copies live in buf1 (dead during FINAL)
    int* rpA2 = (int*)buf1;
    int* rpH2 = rpA2 + (NTOT + 1);

    // ---- build CSR (once; reused across all 3 layers) ----
    hipMemsetAsync(cntA, 0, (size_t)2 * NBK * sizeof(int), stream);
    bucket_count<<<512, 1024, 0, stream>>>(adj_row, hp_row, cntA, cntH);
    bucket_scan<<<1, 64, 0, stream>>>(cntA, cntH, baseA, baseH, gcurA, gcurH);
    wc_scatter<<<512, 1024, 0, stream>>>(adj_row, adj_col, adj_val,
                                         hp_row, hp_col, hp_val,
                                         gcurA, gcurH, stA, stH);
    bucket_csr<<<2 * NBK, 1024, 0, stream>>>(stA, stH, baseA, baseH, rpA, rpH, edA, edH);

    const int gridF = NTOT / TILE;            // 9375
    const int gridL = (2 * BATCH) / TILE;     // 512

    // ---- layer 0: (ue,ie) -> buf1, two half-column passes ----
    fused_passA<true><<<gridF, 256, 0, stream>>>(
        nullptr, user_emb, item_emb, rpA, edA, rpH, edH, buf1);
    fused_passB<true><<<gridF, 256, 0, stream>>>(
        nullptr, user_emb, item_emb, rpA, edA, rpH, edH, W, bias, buf1);
    // ---- layer 1: buf1 -> buf0 ----
    fused_passA<false><<<gridF, 256, 0, stream>>>(
        buf1, nullptr, nullptr, rpA, edA, rpH, edH, buf0);
    fused_passB<false><<<gridF, 256, 0, stream>>>(
        buf1, nullptr, nullptr, rpA, edA, rpH, edH,
        W + (size_t)2 * E * E, bias + E, buf0);

    // relocate rowptrs out of d_out, then FINAL overwrites d_out
    copy_int<<<(2 * (NTOT + 1) + 255) / 256, 256, 0, stream>>>(rpA, rpA2, 2 * (NTOT + 1));
    fused_final<<<gridL, 256, 0, stream>>>(
        buf0, rpA2, edA, rpH2, edH,
        W + (size_t)4 * E * E, bias + 2 * E, users, items, out);
}

// Round 10
// 1817.883 us; speedup vs baseline: 1.5950x; 1.1277x over previous
//
#include <hip/hip_runtime.h>

#define N_USERS 100000
#define N_ITEMS 50000
#define NTOT    150000        // N_USERS + N_ITEMS
#define E       128
#define NNZ     4800000
#define BATCH   4096
#define TILE    16            // rows per fused block (150000 = 16*9375, 8192 = 16*512)
#define BSH     10            // log2(rows per bucket)
#define BROWS   1024          // rows per bucket
#define NBK     147           // ceil(NTOT / BROWS)
#define SLOT    16            // write-combine entries per bucket

typedef int v4i __attribute__((ext_vector_type(4)));

// ---- load helpers ----
__device__ __forceinline__ int   ldnt_i(const int* p)   { return __builtin_nontemporal_load(p); }
__device__ __forceinline__ float ldnt_f(const float* p) { return __builtin_nontemporal_load(p); }
__device__ __forceinline__ v4i   ld_v4(const void* p)   { return *(const v4i*)p; }

// ---------------------------------------------------------------------------
// Build 1: per-bucket edge counts via LDS histograms.
__global__ __launch_bounds__(1024) void bucket_count(const int* __restrict__ rowA,
                                                     const int* __restrict__ rowH,
                                                     int* __restrict__ cntA,
                                                     int* __restrict__ cntH) {
    __shared__ int c[2 * NBK];
    for (int i = threadIdx.x; i < 2 * NBK; i += 1024) c[i] = 0;
    __syncthreads();
    int i = blockIdx.x * 1024 + threadIdx.x;
    const int stride = gridDim.x * 1024;
    for (; i < NNZ; i += stride) {
        atomicAdd(&c[ldnt_i(rowA + i) >> BSH], 1);
        atomicAdd(&c[NBK + (ldnt_i(rowH + i) >> BSH)], 1);
    }
    __syncthreads();
    for (int j = threadIdx.x; j < 2 * NBK; j += 1024) {
        const int v = c[j];
        if (v) atomicAdd(j < NBK ? (cntA + j) : (cntH + (j - NBK)), v);
    }
}

// Build 2: tiny serial scans -> bucket bases + scatter cursors.
__global__ __launch_bounds__(64) void bucket_scan(const int* __restrict__ cntA,
                                                  const int* __restrict__ cntH,
                                                  int* __restrict__ baseA, int* __restrict__ baseH,
                                                  int* __restrict__ gcurA, int* __restrict__ gcurH) {
    const int t = threadIdx.x;
    if (t == 0) {
        int run = 0;
        for (int j = 0; j < NBK; ++j) { baseA[j] = run; gcurA[j] = run; run += cntA[j]; }
        baseA[NBK] = run;
    } else if (t == 1) {
        int run = 0;
        for (int j = 0; j < NBK; ++j) { baseH[j] = run; gcurH[j] = run; run += cntH[j]; }
        baseH[NBK] = run;
    }
}

// Build 3: write-combining bucket scatter (stages (rl10<<18|col, val) by bucket).
__global__ __launch_bounds__(1024) void wc_scatter(const int* __restrict__ rowA, const int* __restrict__ colA,
                                                   const float* __restrict__ valA,
                                                   const int* __restrict__ rowH, const int* __restrict__ colH,
                                                   const float* __restrict__ valH,
                                                   int* __restrict__ gcurA, int* __restrict__ gcurH,
                                                   int2* __restrict__ stA, int2* __restrict__ stH) {
    __shared__ int  lcnt[2 * NBK];
    __shared__ int2 lent[2 * NBK * SLOT];
    for (int i = threadIdx.x; i < 2 * NBK; i += 1024) lcnt[i] = 0;
    __syncthreads();
    const int stride = gridDim.x * 1024;
    const int rounds = (NNZ + stride - 1) / stride;
    for (int rd = 0; rd < rounds; ++rd) {
        const int i = rd * stride + blockIdx.x * 1024 + threadIdx.x;
        if (i < NNZ) {
            {
                const int r = ldnt_i(rowA + i), cc = ldnt_i(colA + i);
                const float v = ldnt_f(valA + i);
                const int b = r >> BSH;
                const int2 pk = make_int2(((r & (BROWS - 1)) << 18) | cc, __float_as_int(v));
                const int n = atomicAdd(&lcnt[b], 1);
                if (n < SLOT) lent[b * SLOT + n] = pk;
                else          stA[atomicAdd(&gcurA[b], 1)] = pk;
            }
            {
                const int r = ldnt_i(rowH + i), cc = ldnt_i(colH + i);
                const float v = ldnt_f(valH + i);
                const int b = r >> BSH;
                const int gb = NBK + b;
                const int2 pk = make_int2(((r & (BROWS - 1)) << 18) | cc, __float_as_int(v));
                const int n = atomicAdd(&lcnt[gb], 1);
                if (n < SLOT) lent[gb * SLOT + n] = pk;
                else          stH[atomicAdd(&gcurH[b], 1)] = pk;
            }
        }
        __syncthreads();
        const int thresh = (rd == rounds - 1) ? 1 : 8;
        for (int gb = threadIdx.x; gb < 2 * NBK; gb += 1024) {
            int n = lcnt[gb]; if (n > SLOT) n = SLOT;
            if (n >= thresh) {
                int*  gc = (gb < NBK) ? &gcurA[gb] : &gcurH[gb - NBK];
                int2* st = (gb < NBK) ? stA : stH;
                const int p = atomicAdd(gc, n);
                for (int j = 0; j < n; ++j) st[p + j] = lent[gb * SLOT + j];
                lcnt[gb] = 0;
            }
        }
        __syncthreads();
    }
}

// Build 4: per-bucket exact CSR + rowptr. Records carry COL ONLY (masked).
__global__ __launch_bounds__(1024) void bucket_csr(const int2* __restrict__ stA, const int2* __restrict__ stH,
                                                   const int* __restrict__ baseA, const int* __restrict__ baseH,
                                                   int* __restrict__ rpA, int* __restrict__ rpH,
                                                   int2* __restrict__ edA, int2* __restrict__ edH) {
    const int isH = blockIdx.x >= NBK;
    const int b   = isH ? blockIdx.x - NBK : blockIdx.x;
    const int2* st   = isH ? stH   : stA;
    const int*  base = isH ? baseH : baseA;
    int*  rp = isH ? rpH : rpA;
    int2* ed = isH ? edH : edA;
    const int s = base[b], e = base[b + 1];
    const int t = threadIdx.x, lane = t & 63, wv = t >> 6;
    __shared__ int cnt[BROWS];
    __shared__ int wsum[16], woff[16];
    cnt[t] = 0;
    __syncthreads();
    for (int i = s + t; i < e; i += 1024) atomicAdd(&cnt[st[i].x >> 18], 1);
    __syncthreads();
    const int v = cnt[t];
    int x = v;
    #pragma unroll
    for (int off = 1; off < 64; off <<= 1) {
        const int n = __shfl_up(x, off);
        if (lane >= off) x += n;
    }
    if (lane == 63) wsum[wv] = x;
    __syncthreads();
    if (t == 0) { int acc = 0; for (int w = 0; w < 16; ++w) { woff[w] = acc; acc += wsum[w]; } }
    __syncthreads();
    const int excl = woff[wv] + (x - v);
    const int rglob = (b << BSH) + t;
    if (rglob < NTOT) rp[rglob] = s + excl;
    __syncthreads();
    cnt[t] = excl;
    __syncthreads();
    for (int i = s + t; i < e; i += 1024) {
        const int2 pk = st[i];
        const int rl = pk.x >> 18;
        const int p = s + atomicAdd(&cnt[rl], 1);
        ed[p] = make_int2(pk.x & 0x3FFFF, pk.y);   // col only
    }
    if (t == 0 && b == 0) rp[NTOT] = NNZ;
}

// generic int copy (rowptr relocation before the FINAL layer)
__global__ __launch_bounds__(256) void copy_int(const int* __restrict__ src,
                                                int* __restrict__ dst, int n) {
    const int i = blockIdx.x * blockDim.x + threadIdx.x;
    if (i < n) dst[i] = src[i];
}

// ---------------------------------------------------------------------------
// Row base as float4*, layer 0 reads straight from the input embeddings.
template<bool FIRST>
__device__ __forceinline__ const float4* rowbase(int c, const float* __restrict__ ue,
                                                 const float* __restrict__ ie,
                                                 const float* __restrict__ A) {
    if constexpr (FIRST)
        return (c < N_USERS) ? ((const float4*)ue + (size_t)c * (E / 4))
                             : ((const float4*)ie + (size_t)(c - N_USERS) * (E / 4));
    else
        return (const float4*)A + (size_t)c * (E / 4);
}

template<bool FIRST>
__device__ __forceinline__ void pairfma(v4i q, const float* __restrict__ ue,
                                        const float* __restrict__ ie,
                                        const float* __restrict__ A,
                                        int sub, int half, float4& acc) {
    const int   c = half ? q[2] : q[0];
    const float v = __int_as_float(half ? q[3] : q[1]);
    const float4 xv = rowbase<FIRST>(c, ue, ie, A)[sub];
    acc.x = fmaf(v, xv.x, acc.x);
    acc.y = fmaf(v, xv.y, acc.y);
    acc.z = fmaf(v, xv.z, acc.z);
    acc.w = fmaf(v, xv.w, acc.w);
}

// Accumulate one CSR row: 2 edges per gather instruction (lanes 0-31 = even
// edge, 32-63 = odd edge; each lane a 16B slice of the 512B row).
template<bool FIRST>
__device__ __forceinline__ float4 row_accum(const int* __restrict__ rp,
                                            const int2* __restrict__ ed,
                                            const float* __restrict__ ue,
                                            const float* __restrict__ ie,
                                            const float* __restrict__ A,
                                            int r, int sub, int half) {
    const int s = rp[r];
    const int e = rp[r + 1];
    float4 accA = {0.f, 0.f, 0.f, 0.f};
    float4 accB = {0.f, 0.f, 0.f, 0.f};
    int i = s;
    if (i < e && (i & 1)) {                 // leading edge to even-align pairs
        const int2 t0 = ed[i];
        const float v = half ? 0.f : __int_as_float(t0.y);
        const float4 xv = rowbase<FIRST>(t0.x, ue, ie, A)[sub];
        accA.x = fmaf(v, xv.x, accA.x); accA.y = fmaf(v, xv.y, accA.y);
        accA.z = fmaf(v, xv.z, accA.z); accA.w = fmaf(v, xv.w, accA.w);
        ++i;
    }
    for (; i + 7 < e; i += 8) {             // 4 pairs = 8 edges
        const v4i q0 = ld_v4(ed + i);
        const v4i q1 = ld_v4(ed + i + 2);
        const v4i q2 = ld_v4(ed + i + 4);
        const v4i q3 = ld_v4(ed + i + 6);
        pairfma<FIRST>(q0, ue, ie, A, sub, half, accA);
        pairfma<FIRST>(q1, ue, ie, A, sub, half, accB);
        pairfma<FIRST>(q2, ue, ie, A, sub, half, accA);
        pairfma<FIRST>(q3, ue, ie, A, sub, half, accB);
    }
    for (; i + 1 < e; i += 2) {
        const v4i q = ld_v4(ed + i);
        pairfma<FIRST>(q, ue, ie, A, sub, half, accA);
    }
    if (i < e) {                            // trailing single edge
        const int2 t0 = ed[i];
        const float v = half ? 0.f : __int_as_float(t0.y);
        const float4 xv = rowbase<FIRST>(t0.x, ue, ie, A)[sub];
        accA.x = fmaf(v, xv.x, accA.x); accA.y = fmaf(v, xv.y, accA.y);
        accA.z = fmaf(v, xv.z, accA.z); accA.w = fmaf(v, xv.w, accA.w);
    }
    return make_float4(accA.x + accB.x, accA.y + accB.y,
                       accA.z + accB.z, accA.w + accB.w);
}

// ---------------------------------------------------------------------------
// Fused layer (round-6 structure, proven 720us): TILE rows of pos (adj) and
// dis (hp) into LDS via full-row pair-gather, then Linear, write out.
template<bool FIRST>
__global__ __launch_bounds__(256) void fused_layer(
    const float* __restrict__ A,
    const float* __restrict__ ue, const float* __restrict__ ie,
    const int* __restrict__ rpA, const int2* __restrict__ edA,
    const int* __restrict__ rpH, const int2* __restrict__ edH,
    const float* __restrict__ Wk, const float* __restrict__ bk,
    float* __restrict__ out) {
    __shared__ float sP[TILE][E];
    __shared__ float sD[TILE][E];
    const int t    = threadIdx.x;
    const int lane = t & 63;
    const int sub  = lane & 31;              // 16B slice within the row
    const int half = lane >> 5;              // which edge of the pair
    const int wv   = t >> 6;                 // wave 0..3, 4 rows each
    const int r0   = blockIdx.x * TILE;

    #pragma unroll
    for (int rl = 0; rl < 4; ++rl) {
        const int r = r0 + wv * 4 + rl;
        const float4 ap = row_accum<FIRST>(rpA, edA, ue, ie, A, r, sub, half);
        const float4 ad = row_accum<FIRST>(rpH, edH, ue, ie, A, r, sub, half);
        float4 send = half ? ap : ad;        // half0 finalizes pos, half1 dis
        float4 recv;
        recv.x = __shfl_xor(send.x, 32);
        recv.y = __shfl_xor(send.y, 32);
        recv.z = __shfl_xor(send.z, 32);
        recv.w = __shfl_xor(send.w, 32);
        if (!half) {
            ((float4*)&sP[wv * 4 + rl][0])[sub] = make_float4(ap.x + recv.x, ap.y + recv.y,
                                                              ap.z + recv.z, ap.w + recv.w);
        } else {
            ((float4*)&sD[wv * 4 + rl][0])[sub] = make_float4(ad.x + recv.x, ad.y + recv.y,
                                                              ad.z + recv.z, ad.w + recv.w);
        }
    }
    __syncthreads();

    // ---- phase 2: [TILE,256] @ [256,128] + bias ----
    const int j = t & (E - 1);
    const int h = t >> 7;
    float acc[8];
    const float bj = bk[j];
    #pragma unroll
    for (int rr = 0; rr < 8; ++rr) acc[rr] = bj;
    #pragma unroll 4
    for (int i = 0; i < E; ++i) {
        const float w = Wk[(size_t)i * E + j];
        #pragma unroll
        for (int rr = 0; rr < 8; ++rr) acc[rr] = fmaf(sP[h * 8 + rr][i], w, acc[rr]);
    }
    #pragma unroll 4
    for (int i = 0; i < E; ++i) {
        const float w = Wk[(size_t)(E + i) * E + j];
        #pragma unroll
        for (int rr = 0; rr < 8; ++rr) acc[rr] = fmaf(sD[h * 8 + rr][i], w, acc[rr]);
    }
    #pragma unroll
    for (int rr = 0; rr < 8; ++rr)
        out[(size_t)(r0 + h * 8 + rr) * E + j] = acc[rr];
}

// ---------------------------------------------------------------------------
// FINAL layer: full-row pair-gather over per-row CSR spans for the 8192
// requested rows, then Linear, writing d_out.
__device__ __forceinline__ void pf_full(v4i q, const float* __restrict__ A,
                                        int sub, int half, float4& acc) {
    const int   c = half ? q[2] : q[0];
    const float v = __int_as_float(half ? q[3] : q[1]);
    const float4 xv = ((const float4*)(A + (size_t)c * E))[sub];
    acc.x = fmaf(v, xv.x, acc.x);
    acc.y = fmaf(v, xv.y, acc.y);
    acc.z = fmaf(v, xv.z, acc.z);
    acc.w = fmaf(v, xv.w, acc.w);
}

__device__ __forceinline__ float4 accum_full(int s, int e, const int2* __restrict__ ed,
                                             const float* __restrict__ A, int sub, int half) {
    float4 a{0.f,0.f,0.f,0.f}, b{0.f,0.f,0.f,0.f};
    int i = s;
    if (i < e && (i & 1)) {
        const int2 t0 = ed[i];
        const float v = half ? 0.f : __int_as_float(t0.y);
        const float4 xv = ((const float4*)(A + (size_t)t0.x * E))[sub];
        a.x = fmaf(v, xv.x, a.x); a.y = fmaf(v, xv.y, a.y);
        a.z = fmaf(v, xv.z, a.z); a.w = fmaf(v, xv.w, a.w);
        ++i;
    }
    for (; i + 7 < e; i += 8) {
        const v4i q0 = ld_v4(ed + i);
        const v4i q1 = ld_v4(ed + i + 2);
        const v4i q2 = ld_v4(ed + i + 4);
        const v4i q3 = ld_v4(ed + i + 6);
        pf_full(q0, A, sub, half, a);
        pf_full(q1, A, sub, half, b);
        pf_full(q2, A, sub, half, a);
        pf_full(q3, A, sub, half, b);
    }
    for (; i + 1 < e; i += 2) {
        const v4i q = ld_v4(ed + i);
        pf_full(q, A, sub, half, a);
    }
    if (i < e) {
        const int2 t0 = ed[i];
        const float v = half ? 0.f : __int_as_float(t0.y);
        const float4 xv = ((const float4*)(A + (size_t)t0.x * E))[sub];
        a.x = fmaf(v, xv.x, a.x); a.y = fmaf(v, xv.y, a.y);
        a.z = fmaf(v, xv.z, a.z); a.w = fmaf(v, xv.w, a.w);
    }
    return make_float4(a.x + b.x, a.y + b.y, a.z + b.z, a.w + b.w);
}

__global__ __launch_bounds__(256) void fused_final(
    const float* __restrict__ A,
    const int* __restrict__ rpA, const int2* __restrict__ edA,
    const int* __restrict__ rpH, const int2* __restrict__ edH,
    const float* __restrict__ Wk, const float* __restrict__ bk,
    const int* __restrict__ users, const int* __restrict__ items,
    float* __restrict__ out) {
    __shared__ float sP[TILE][E];
    __shared__ float sD[TILE][E];
    const int t = threadIdx.x, lane = t & 63, sub = lane & 31, half = lane >> 5, wv = t >> 6;

    #pragma unroll
    for (int rl = 0; rl < 4; ++rl) {
        const int slot = blockIdx.x * TILE + wv * 4 + rl;
        const int r = (slot < BATCH) ? users[slot] : (N_USERS + items[slot - BATCH]);
        const float4 ap = accum_full(rpA[r], rpA[r + 1], edA, A, sub, half);
        const float4 ad = accum_full(rpH[r], rpH[r + 1], edH, A, sub, half);
        float4 send = half ? ap : ad;
        float4 recv;
        recv.x = __shfl_xor(send.x, 32);
        recv.y = __shfl_xor(send.y, 32);
        recv.z = __shfl_xor(send.z, 32);
        recv.w = __shfl_xor(send.w, 32);
        if (!half) {
            ((float4*)&sP[wv * 4 + rl][0])[sub] = make_float4(ap.x + recv.x, ap.y + recv.y,
                                                              ap.z + recv.z, ap.w + recv.w);
        } else {
            ((float4*)&sD[wv * 4 + rl][0])[sub] = make_float4(ad.x + recv.x, ad.y + recv.y,
                                                              ad.z + recv.z, ad.w + recv.w);
        }
    }
    __syncthreads();

    const int j = t & (E - 1);
    const int h = t >> 7;
    float acc[8];
    const float bj = bk[j];
    #pragma unroll
    for (int rr = 0; rr < 8; ++rr) acc[rr] = bj;
    #pragma unroll 4
    for (int i = 0; i < E; ++i) {
        const float w = Wk[(size_t)i * E + j];
        #pragma unroll
        for (int rr = 0; rr < 8; ++rr) acc[rr] = fmaf(sP[h * 8 + rr][i], w, acc[rr]);
    }
    #pragma unroll 4
    for (int i = 0; i < E; ++i) {
        const float w = Wk[(size_t)(E + i) * E + j];
        #pragma unroll
        for (int rr = 0; rr < 8; ++rr) acc[rr] = fmaf(sD[h * 8 + rr][i], w, acc[rr]);
    }
    #pragma unroll
    for (int rr = 0; rr < 8; ++rr)
        out[(size_t)(blockIdx.x * TILE + h * 8 + rr) * E + j] = acc[rr];
}

// ---------------------------------------------------------------------------
extern "C" void kernel_launch(void* const* d_in, const int* in_sizes, int n_in,
                              void* d_out, int out_size, void* d_ws, size_t ws_size,
                              hipStream_t stream) {
    const float* user_emb = (const float*)d_in[0];
    const float* item_emb = (const float*)d_in[1];
    const float* adj_val  = (const float*)d_in[2];
    const float* hp_val   = (const float*)d_in[3];
    const float* W        = (const float*)d_in[4];
    const float* bias     = (const float*)d_in[5];
    const int*   adj_row  = (const int*)d_in[6];
    const int*   adj_col  = (const int*)d_in[7];
    const int*   hp_row   = (const int*)d_in[8];
    const int*   hp_col   = (const int*)d_in[9];
    const int*   users    = (const int*)d_in[10];
    const int*   items    = (const int*)d_in[11];
    float* out = (float*)d_out;

    // ---- workspace: exactly 230,400,000 B (proven available) ----
    float* buf0 = (float*)d_ws;                       // ego ping / build staging
    float* buf1 = buf0 + (size_t)NTOT * E;            // ego pong / final rowptrs
    int2*  edA  = (int2*)(buf1 + (size_t)NTOT * E);   // CSR edges A   38.4 MB
    int2*  edH  = edA + NNZ;                          // CSR edges H   38.4 MB
    int2*  stA  = (int2*)buf0;                        // staging aliases buf0
    int2*  stH  = stA + NNZ;

    // ---- metadata in d_out (4.19 MB; fully overwritten by FINAL) ----
    int* rpA   = (int*)d_out;                         // NTOT+1
    int* rpH   = rpA + (NTOT + 1);                    // NTOT+1
    int* cntA  = rpH + (NTOT + 1);
    int* cntH  = cntA + NBK;
    int* baseA = cntH + NBK;
    int* baseH = baseA + (NBK + 1);
    int* gcurA = baseH + (NBK + 1);
    int* gcurH = gcurA + NBK;

    // FINAL-time rowptr copies live in buf1 (dead during FINAL)
    int* rpA2 = (int*)buf1;
    int* rpH2 = rpA2 + (NTOT + 1);

    // ---- build CSR (once; reused across all 3 layers) ----
    hipMemsetAsync(cntA, 0, (size_t)2 * NBK * sizeof(int), stream);
    bucket_count<<<512, 1024, 0, stream>>>(adj_row, hp_row, cntA, cntH);
    bucket_scan<<<1, 64, 0, stream>>>(cntA, cntH, baseA, baseH, gcurA, gcurH);
    wc_scatter<<<512, 1024, 0, stream>>>(adj_row, adj_col, adj_val,
                                         hp_row, hp_col, hp_val,
                                         gcurA, gcurH, stA, stH);
    bucket_csr<<<2 * NBK, 1024, 0, stream>>>(stA, stH, baseA, baseH, rpA, rpH, edA, edH);

    const int gridF = NTOT / TILE;            // 9375
    const int gridL = (2 * BATCH) / TILE;     // 512

    // ---- layer 0: (ue,ie) -> buf1 ----
    fused_layer<true><<<gridF, 256, 0, stream>>>(
        nullptr, user_emb, item_emb, rpA, edA, rpH, edH, W, bias, buf1);
    // ---- layer 1: buf1 -> buf0 ----
    fused_layer<false><<<gridF, 256, 0, stream>>>(
        buf1, nullptr, nullptr, rpA, edA, rpH, edH,
        W + (size_t)2 * E * E, bias + E, buf0);

    // relocate rowptrs out of d_out, then FINAL overwrites d_out
    copy_int<<<(2 * (NTOT + 1) + 255) / 256, 256, 0, stream>>>(rpA, rpA2, 2 * (NTOT + 1));
    // ---- layer 2: buf0 -> d_out (only the 8192 requested rows) ----
    fused_final<<<gridL, 256, 0, stream>>>(
        buf0, rpA2, edA, rpH2, edH,
        W + (size_t)4 * E * E, bias + 2 * E, users, items, out);
}

// Round 11
// 1708.112 us; speedup vs baseline: 1.6975x; 1.0643x over previous
//
#include <hip/hip_runtime.h>

#define N_USERS 100000
#define N_ITEMS 50000
#define NTOT    150000        // N_USERS + N_ITEMS
#define E       128
#define NNZ     4800000
#define BATCH   4096
#define TILE    16            // rows per fused block (150000 = 16*9375, 8192 = 16*512)
#define BSH     10            // log2(rows per bucket)
#define BROWS   1024          // rows per bucket
#define NBK     147           // ceil(NTOT / BROWS)
#define SLOT    24            // write-combine entries per bucket (56KB LDS)

typedef int v4i __attribute__((ext_vector_type(4)));

__device__ __forceinline__ v4i ld_v4(const void* p) { return *(const v4i*)p; }

// ---------------------------------------------------------------------------
// Build 1: per-bucket edge counts via LDS histograms. 2 edges/thread/iter.
__global__ __launch_bounds__(1024) void bucket_count(const int* __restrict__ rowA,
                                                     const int* __restrict__ rowH,
                                                     int* __restrict__ cntA,
                                                     int* __restrict__ cntH) {
    __shared__ int c[2 * NBK];
    for (int i = threadIdx.x; i < 2 * NBK; i += 1024) c[i] = 0;
    __syncthreads();
    int i = (blockIdx.x * 1024 + threadIdx.x) * 2;          // even; NNZ even
    const int stride = gridDim.x * 2048;
    for (; i < NNZ; i += stride) {
        const int2 ra = *(const int2*)(rowA + i);
        const int2 rh = *(const int2*)(rowH + i);
        atomicAdd(&c[ra.x >> BSH], 1);
        atomicAdd(&c[ra.y >> BSH], 1);
        atomicAdd(&c[NBK + (rh.x >> BSH)], 1);
        atomicAdd(&c[NBK + (rh.y >> BSH)], 1);
    }
    __syncthreads();
    for (int j = threadIdx.x; j < 2 * NBK; j += 1024) {
        const int v = c[j];
        if (v) atomicAdd(j < NBK ? (cntA + j) : (cntH + (j - NBK)), v);
    }
}

// Build 2: tiny serial scans -> bucket bases + scatter cursors.
__global__ __launch_bounds__(64) void bucket_scan(const int* __restrict__ cntA,
                                                  const int* __restrict__ cntH,
                                                  int* __restrict__ baseA, int* __restrict__ baseH,
                                                  int* __restrict__ gcurA, int* __restrict__ gcurH) {
    const int t = threadIdx.x;
    if (t == 0) {
        int run = 0;
        for (int j = 0; j < NBK; ++j) { baseA[j] = run; gcurA[j] = run; run += cntA[j]; }
        baseA[NBK] = run;
    } else if (t == 1) {
        int run = 0;
        for (int j = 0; j < NBK; ++j) { baseH[j] = run; gcurH[j] = run; run += cntH[j]; }
        baseH[NBK] = run;
    }
}

// Build 3: write-combining bucket scatter, 2 edges/adjacency/thread/round.
__global__ __launch_bounds__(1024) void wc_scatter(const int* __restrict__ rowA, const int* __restrict__ colA,
                                                   const float* __restrict__ valA,
                                                   const int* __restrict__ rowH, const int* __restrict__ colH,
                                                   const float* __restrict__ valH,
                                                   int* __restrict__ gcurA, int* __restrict__ gcurH,
                                                   int2* __restrict__ stA, int2* __restrict__ stH) {
    __shared__ int  lcnt[2 * NBK];
    __shared__ int2 lent[2 * NBK * SLOT];
    for (int i = threadIdx.x; i < 2 * NBK; i += 1024) lcnt[i] = 0;
    __syncthreads();
    const int stride = gridDim.x * 2048;
    const int rounds = (NNZ + stride - 1) / stride;
    for (int rd = 0; rd < rounds; ++rd) {
        const int i = rd * stride + (blockIdx.x * 1024 + threadIdx.x) * 2;
        if (i < NNZ) {                       // i even, NNZ even -> i+1 < NNZ
            {   // A edges i, i+1
                const int2   r2 = *(const int2*)(rowA + i);
                const int2   c2 = *(const int2*)(colA + i);
                const float2 v2 = *(const float2*)(valA + i);
                {
                    const int b = r2.x >> BSH;
                    const int2 pk = make_int2(((r2.x & (BROWS - 1)) << 18) | c2.x, __float_as_int(v2.x));
                    const int n = atomicAdd(&lcnt[b], 1);
                    if (n < SLOT) lent[b * SLOT + n] = pk;
                    else          stA[atomicAdd(&gcurA[b], 1)] = pk;
                }
                {
                    const int b = r2.y >> BSH;
                    const int2 pk = make_int2(((r2.y & (BROWS - 1)) << 18) | c2.y, __float_as_int(v2.y));
                    const int n = atomicAdd(&lcnt[b], 1);
                    if (n < SLOT) lent[b * SLOT + n] = pk;
                    else          stA[atomicAdd(&gcurA[b], 1)] = pk;
                }
            }
            {   // H edges i, i+1
                const int2   r2 = *(const int2*)(rowH + i);
                const int2   c2 = *(const int2*)(colH + i);
                const float2 v2 = *(const float2*)(valH + i);
                {
                    const int gb = NBK + (r2.x >> BSH);
                    const int2 pk = make_int2(((r2.x & (BROWS - 1)) << 18) | c2.x, __float_as_int(v2.x));
                    const int n = atomicAdd(&lcnt[gb], 1);
                    if (n < SLOT) lent[gb * SLOT + n] = pk;
                    else          stH[atomicAdd(&gcurH[gb - NBK], 1)] = pk;
                }
                {
                    const int gb = NBK + (r2.y >> BSH);
                    const int2 pk = make_int2(((r2.y & (BROWS - 1)) << 18) | c2.y, __float_as_int(v2.y));
                    const int n = atomicAdd(&lcnt[gb], 1);
                    if (n < SLOT) lent[gb * SLOT + n] = pk;
                    else          stH[atomicAdd(&gcurH[gb - NBK], 1)] = pk;
                }
            }
        }
        __syncthreads();
        const int thresh = (rd == rounds - 1) ? 1 : 8;
        for (int gb = threadIdx.x; gb < 2 * NBK; gb += 1024) {
            int n = lcnt[gb]; if (n > SLOT) n = SLOT;
            if (n >= thresh) {
                int*  gc = (gb < NBK) ? &gcurA[gb] : &gcurH[gb - NBK];
                int2* st = (gb < NBK) ? stA : stH;
                const int p = atomicAdd(gc, n);
                for (int j = 0; j < n; ++j) st[p + j] = lent[gb * SLOT + j];
                lcnt[gb] = 0;
            }
        }
        __syncthreads();
    }
}

// Build 4: per-bucket exact CSR + rowptr. Records carry COL ONLY (masked).
__global__ __launch_bounds__(1024) void bucket_csr(const int2* __restrict__ stA, const int2* __restrict__ stH,
                                                   const int* __restrict__ baseA, const int* __restrict__ baseH,
                                                   int* __restrict__ rpA, int* __restrict__ rpH,
                                                   int2* __restrict__ edA, int2* __restrict__ edH) {
    const int isH = blockIdx.x >= NBK;
    const int b   = isH ? blockIdx.x - NBK : blockIdx.x;
    const int2* st   = isH ? stH   : stA;
    const int*  base = isH ? baseH : baseA;
    int*  rp = isH ? rpH : rpA;
    int2* ed = isH ? edH : edA;
    const int s = base[b], e = base[b + 1];
    const int t = threadIdx.x, lane = t & 63, wv = t >> 6;
    __shared__ int cnt[BROWS];
    __shared__ int wsum[16], woff[16];
    cnt[t] = 0;
    __syncthreads();
    for (int i = s + t; i < e; i += 1024) atomicAdd(&cnt[st[i].x >> 18], 1);
    __syncthreads();
    const int v = cnt[t];
    int x = v;
    #pragma unroll
    for (int off = 1; off < 64; off <<= 1) {
        const int n = __shfl_up(x, off);
        if (lane >= off) x += n;
    }
    if (lane == 63) wsum[wv] = x;
    __syncthreads();
    if (t == 0) { int acc = 0; for (int w = 0; w < 16; ++w) { woff[w] = acc; acc += wsum[w]; } }
    __syncthreads();
    const int excl = woff[wv] + (x - v);
    const int rglob = (b << BSH) + t;
    if (rglob < NTOT) rp[rglob] = s + excl;
    __syncthreads();
    cnt[t] = excl;
    __syncthreads();
    for (int i = s + t; i < e; i += 1024) {
        const int2 pk = st[i];
        const int rl = pk.x >> 18;
        const int p = s + atomicAdd(&cnt[rl], 1);
        ed[p] = make_int2(pk.x & 0x3FFFF, pk.y);   // col only
    }
    if (t == 0 && b == 0) rp[NTOT] = NNZ;
}

// generic int copy (rowptr relocation before the FINAL layer)
__global__ __launch_bounds__(256) void copy_int(const int* __restrict__ src,
                                                int* __restrict__ dst, int n) {
    const int i = blockIdx.x * blockDim.x + threadIdx.x;
    if (i < n) dst[i] = src[i];
}

// ---------------------------------------------------------------------------
// Row base as float4*, layer 0 reads straight from the input embeddings.
template<bool FIRST>
__device__ __forceinline__ const float4* rowbase(int c, const float* __restrict__ ue,
                                                 const float* __restrict__ ie,
                                                 const float* __restrict__ A) {
    if constexpr (FIRST)
        return (c < N_USERS) ? ((const float4*)ue + (size_t)c * (E / 4))
                             : ((const float4*)ie + (size_t)(c - N_USERS) * (E / 4));
    else
        return (const float4*)A + (size_t)c * (E / 4);
}

template<bool FIRST>
__device__ __forceinline__ void pairfma(v4i q, const float* __restrict__ ue,
                                        const float* __restrict__ ie,
                                        const float* __restrict__ A,
                                        int sub, int half, float4& acc) {
    const int   c = half ? q[2] : q[0];
    const float v = __int_as_float(half ? q[3] : q[1]);
    const float4 xv = rowbase<FIRST>(c, ue, ie, A)[sub];
    acc.x = fmaf(v, xv.x, acc.x);
    acc.y = fmaf(v, xv.y, acc.y);
    acc.z = fmaf(v, xv.z, acc.z);
    acc.w = fmaf(v, xv.w, acc.w);
}

// Accumulate one CSR row: 2 edges per gather instruction (lanes 0-31 = even
// edge, 32-63 = odd edge; each lane a 16B slice of the 512B row).
template<bool FIRST>
__device__ __forceinline__ float4 row_accum(const int* __restrict__ rp,
                                            const int2* __restrict__ ed,
                                            const float* __restrict__ ue,
                                            const float* __restrict__ ie,
                                            const float* __restrict__ A,
                                            int r, int sub, int half) {
    const int s = rp[r];
    const int e = rp[r + 1];
    float4 accA = {0.f, 0.f, 0.f, 0.f};
    float4 accB = {0.f, 0.f, 0.f, 0.f};
    int i = s;
    if (i < e && (i & 1)) {                 // leading edge to even-align pairs
        const int2 t0 = ed[i];
        const float v = half ? 0.f : __int_as_float(t0.y);
        const float4 xv = rowbase<FIRST>(t0.x, ue, ie, A)[sub];
        accA.x = fmaf(v, xv.x, accA.x); accA.y = fmaf(v, xv.y, accA.y);
        accA.z = fmaf(v, xv.z, accA.z); accA.w = fmaf(v, xv.w, accA.w);
        ++i;
    }
    for (; i + 7 < e; i += 8) {             // 4 pairs = 8 edges
        const v4i q0 = ld_v4(ed + i);
        const v4i q1 = ld_v4(ed + i + 2);
        const v4i q2 = ld_v4(ed + i + 4);
        const v4i q3 = ld_v4(ed + i + 6);
        pairfma<FIRST>(q0, ue, ie, A, sub, half, accA);
        pairfma<FIRST>(q1, ue, ie, A, sub, half, accB);
        pairfma<FIRST>(q2, ue, ie, A, sub, half, accA);
        pairfma<FIRST>(q3, ue, ie, A, sub, half, accB);
    }
    for (; i + 1 < e; i += 2) {
        const v4i q = ld_v4(ed + i);
        pairfma<FIRST>(q, ue, ie, A, sub, half, accA);
    }
    if (i < e) {                            // trailing single edge
        const int2 t0 = ed[i];
        const float v = half ? 0.f : __int_as_float(t0.y);
        const float4 xv = rowbase<FIRST>(t0.x, ue, ie, A)[sub];
        accA.x = fmaf(v, xv.x, accA.x); accA.y = fmaf(v, xv.y, accA.y);
        accA.z = fmaf(v, xv.z, accA.z); accA.w = fmaf(v, xv.w, accA.w);
    }
    return make_float4(accA.x + accB.x, accA.y + accB.y,
                       accA.z + accB.z, accA.w + accB.w);
}

// ---------------------------------------------------------------------------
// Fused layer (proven 720us): TILE rows of pos (adj) and dis (hp) into LDS
// via full-row pair-gather, then Linear, write out.
template<bool FIRST>
__global__ __launch_bounds__(256) void fused_layer(
    const float* __restrict__ A,
    const float* __restrict__ ue, const float* __restrict__ ie,
    const int* __restrict__ rpA, const int2* __restrict__ edA,
    const int* __restrict__ rpH, const int2* __restrict__ edH,
    const float* __restrict__ Wk, const float* __restrict__ bk,
    float* __restrict__ out) {
    __shared__ float sP[TILE][E];
    __shared__ float sD[TILE][E];
    const int t    = threadIdx.x;
    const int lane = t & 63;
    const int sub  = lane & 31;              // 16B slice within the row
    const int half = lane >> 5;              // which edge of the pair
    const int wv   = t >> 6;                 // wave 0..3, 4 rows each
    const int r0   = blockIdx.x * TILE;

    #pragma unroll
    for (int rl = 0; rl < 4; ++rl) {
        const int r = r0 + wv * 4 + rl;
        const float4 ap = row_accum<FIRST>(rpA, edA, ue, ie, A, r, sub, half);
        const float4 ad = row_accum<FIRST>(rpH, edH, ue, ie, A, r, sub, half);
        float4 send = half ? ap : ad;        // half0 finalizes pos, half1 dis
        float4 recv;
        recv.x = __shfl_xor(send.x, 32);
        recv.y = __shfl_xor(send.y, 32);
        recv.z = __shfl_xor(send.z, 32);
        recv.w = __shfl_xor(send.w, 32);
        if (!half) {
            ((float4*)&sP[wv * 4 + rl][0])[sub] = make_float4(ap.x + recv.x, ap.y + recv.y,
                                                              ap.z + recv.z, ap.w + recv.w);
        } else {
            ((float4*)&sD[wv * 4 + rl][0])[sub] = make_float4(ad.x + recv.x, ad.y + recv.y,
                                                              ad.z + recv.z, ad.w + recv.w);
        }
    }
    __syncthreads();

    // ---- phase 2: [TILE,256] @ [256,128] + bias ----
    const int j = t & (E - 1);
    const int h = t >> 7;
    float acc[8];
    const float bj = bk[j];
    #pragma unroll
    for (int rr = 0; rr < 8; ++rr) acc[rr] = bj;
    #pragma unroll 4
    for (int i = 0; i < E; ++i) {
        const float w = Wk[(size_t)i * E + j];
        #pragma unroll
        for (int rr = 0; rr < 8; ++rr) acc[rr] = fmaf(sP[h * 8 + rr][i], w, acc[rr]);
    }
    #pragma unroll 4
    for (int i = 0; i < E; ++i) {
        const float w = Wk[(size_t)(E + i) * E + j];
        #pragma unroll
        for (int rr = 0; rr < 8; ++rr) acc[rr] = fmaf(sD[h * 8 + rr][i], w, acc[rr]);
    }
    #pragma unroll
    for (int rr = 0; rr < 8; ++rr)
        out[(size_t)(r0 + h * 8 + rr) * E + j] = acc[rr];
}

// ---------------------------------------------------------------------------
// FINAL layer: full-row pair-gather over per-row CSR spans for the 8192
// requested rows, then Linear, writing d_out.
__device__ __forceinline__ void pf_full(v4i q, const float* __restrict__ A,
                                        int sub, int half, float4& acc) {
    const int   c = half ? q[2] : q[0];
    const float v = __int_as_float(half ? q[3] : q[1]);
    const float4 xv = ((const float4*)(A + (size_t)c * E))[sub];
    acc.x = fmaf(v, xv.x, acc.x);
    acc.y = fmaf(v, xv.y, acc.y);
    acc.z = fmaf(v, xv.z, acc.z);
    acc.w = fmaf(v, xv.w, acc.w);
}

__device__ __forceinline__ float4 accum_full(int s, int e, const int2* __restrict__ ed,
                                             const float* __restrict__ A, int sub, int half) {
    float4 a{0.f,0.f,0.f,0.f}, b{0.f,0.f,0.f,0.f};
    int i = s;
    if (i < e && (i & 1)) {
        const int2 t0 = ed[i];
        const float v = half ? 0.f : __int_as_float(t0.y);
        const float4 xv = ((const float4*)(A + (size_t)t0.x * E))[sub];
        a.x = fmaf(v, xv.x, a.x); a.y = fmaf(v, xv.y, a.y);
        a.z = fmaf(v, xv.z, a.z); a.w = fmaf(v, xv.w, a.w);
        ++i;
    }
    for (; i + 7 < e; i += 8) {
        const v4i q0 = ld_v4(ed + i);
        const v4i q1 = ld_v4(ed + i + 2);
        const v4i q2 = ld_v4(ed + i + 4);
        const v4i q3 = ld_v4(ed + i + 6);
        pf_full(q0, A, sub, half, a);
        pf_full(q1, A, sub, half, b);
        pf_full(q2, A, sub, half, a);
        pf_full(q3, A, sub, half, b);
    }
    for (; i + 1 < e; i += 2) {
        const v4i q = ld_v4(ed + i);
        pf_full(q, A, sub, half, a);
    }
    if (i < e) {
        const int2 t0 = ed[i];
        const float v = half ? 0.f : __int_as_float(t0.y);
        const float4 xv = ((const float4*)(A + (size_t)t0.x * E))[sub];
        a.x = fmaf(v, xv.x, a.x); a.y = fmaf(v, xv.y, a.y);
        a.z = fmaf(v, xv.z, a.z); a.w = fmaf(v, xv.w, a.w);
    }
    return make_float4(a.x + b.x, a.y + b.y, a.z + b.z, a.w + b.w);
}

__global__ __launch_bounds__(256) void fused_final(
    const float* __restrict__ A,
    const int* __restrict__ rpA, const int2* __restrict__ edA,
    const int* __restrict__ rpH, const int2* __restrict__ edH,
    const float* __restrict__ Wk, const float* __restrict__ bk,
    const int* __restrict__ users, const int* __restrict__ items,
    float* __restrict__ out) {
    __shared__ float sP[TILE][E];
    __shared__ float sD[TILE][E];
    const int t = threadIdx.x, lane = t & 63, sub = lane & 31, half = lane >> 5, wv = t >> 6;

    #pragma unroll
    for (int rl = 0; rl < 4; ++rl) {
        const int slot = blockIdx.x * TILE + wv * 4 + rl;
        const int r = (slot < BATCH) ? users[slot] : (N_USERS + items[slot - BATCH]);
        const float4 ap = accum_full(rpA[r], rpA[r + 1], edA, A, sub, half);
        const float4 ad = accum_full(rpH[r], rpH[r + 1], edH, A, sub, half);
        float4 send = half ? ap : ad;
        float4 recv;
        recv.x = __shfl_xor(send.x, 32);
        recv.y = __shfl_xor(send.y, 32);
        recv.z = __shfl_xor(send.z, 32);
        recv.w = __shfl_xor(send.w, 32);
        if (!half) {
            ((float4*)&sP[wv * 4 + rl][0])[sub] = make_float4(ap.x + recv.x, ap.y + recv.y,
                                                              ap.z + recv.z, ap.w + recv.w);
        } else {
            ((float4*)&sD[wv * 4 + rl][0])[sub] = make_float4(ad.x + recv.x, ad.y + recv.y,
                                                              ad.z + recv.z, ad.w + recv.w);
        }
    }
    __syncthreads();

    const int j = t & (E - 1);
    const int h = t >> 7;
    float acc[8];
    const float bj = bk[j];
    #pragma unroll
    for (int rr = 0; rr < 8; ++rr) acc[rr] = bj;
    #pragma unroll 4
    for (int i = 0; i < E; ++i) {
        const float w = Wk[(size_t)i * E + j];
        #pragma unroll
        for (int rr = 0; rr < 8; ++rr) acc[rr] = fmaf(sP[h * 8 + rr][i], w, acc[rr]);
    }
    #pragma unroll 4
    for (int i = 0; i < E; ++i) {
        const float w = Wk[(size_t)(E + i) * E + j];
        #pragma unroll
        for (int rr = 0; rr < 8; ++rr) acc[rr] = fmaf(sD[h * 8 + rr][i], w, acc[rr]);
    }
    #pragma unroll
    for (int rr = 0; rr < 8; ++rr)
        out[(size_t)(blockIdx.x * TILE + h * 8 + rr) * E + j] = acc[rr];
}

// ---------------------------------------------------------------------------
extern "C" void kernel_launch(void* const* d_in, const int* in_sizes, int n_in,
                              void* d_out, int out_size, void* d_ws, size_t ws_size,
                              hipStream_t stream) {
    const float* user_emb = (const float*)d_in[0];
    const float* item_emb = (const float*)d_in[1];
    const float* adj_val  = (const float*)d_in[2];
    const float* hp_val   = (const float*)d_in[3];
    const float* W        = (const float*)d_in[4];
    const float* bias     = (const float*)d_in[5];
    const int*   adj_row  = (const int*)d_in[6];
    const int*   adj_col  = (const int*)d_in[7];
    const int*   hp_row   = (const int*)d_in[8];
    const int*   hp_col   = (const int*)d_in[9];
    const int*   users    = (const int*)d_in[10];
    const int*   items    = (const int*)d_in[11];
    float* out = (float*)d_out;

    // ---- workspace: exactly 230,400,000 B (proven available) ----
    float* buf0 = (float*)d_ws;                       // ego ping / build staging
    float* buf1 = buf0 + (size_t)NTOT * E;            // ego pong / final rowptrs
    int2*  edA  = (int2*)(buf1 + (size_t)NTOT * E);   // CSR edges A   38.4 MB
    int2*  edH  = edA + NNZ;                          // CSR edges H   38.4 MB
    int2*  stA  = (int2*)buf0;                        // staging aliases buf0
    int2*  stH  = stA + NNZ;

    // ---- metadata in d_out (4.19 MB; fully overwritten by FINAL) ----
    int* rpA   = (int*)d_out;                         // NTOT+1
    int* rpH   = rpA + (NTOT + 1);                    // NTOT+1
    int* cntA  = rpH + (NTOT + 1);
    int* cntH  = cntA + NBK;
    int* baseA = cntH + NBK;
    int* baseH = baseA + (NBK + 1);
    int* gcurA = baseH + (NBK + 1);
    int* gcurH = gcurA + NBK;

    // FINAL-time rowptr copies live in buf1 (dead during FINAL)
    int* rpA2 = (int*)buf1;
    int* rpH2 = rpA2 + (NTOT + 1);

    // ---- build CSR (once; reused across all 3 layers) ----
    hipMemsetAsync(cntA, 0, (size_t)2 * NBK * sizeof(int), stream);
    bucket_count<<<512, 1024, 0, stream>>>(adj_row, hp_row, cntA, cntH);
    bucket_scan<<<1, 64, 0, stream>>>(cntA, cntH, baseA, baseH, gcurA, gcurH);
    wc_scatter<<<512, 1024, 0, stream>>>(adj_row, adj_col, adj_val,
                                         hp_row, hp_col, hp_val,
                                         gcurA, gcurH, stA, stH);
    bucket_csr<<<2 * NBK, 1024, 0, stream>>>(stA, stH, baseA, baseH, rpA, rpH, edA, edH);

    const int gridF = NTOT / TILE;            // 9375
    const int gridL = (2 * BATCH) / TILE;     // 512

    // ---- layer 0: (ue,ie) -> buf1 ----
    fused_layer<true><<<gridF, 256, 0, stream>>>(
        nullptr, user_emb, item_emb, rpA, edA, rpH, edH, W, bias, buf1);
    // ---- layer 1: buf1 -> buf0 ----
    fused_layer<false><<<gridF, 256, 0, stream>>>(
        buf1, nullptr, nullptr, rpA, edA, rpH, edH,
        W + (size_t)2 * E * E, bias + E, buf0);

    // relocate rowptrs out of d_out, then FINAL overwrites d_out
    copy_int<<<(2 * (NTOT + 1) + 255) / 256, 256, 0, stream>>>(rpA, rpA2, 2 * (NTOT + 1));
    // ---- layer 2: buf0 -> d_out (only the 8192 requested rows) ----
    fused_final<<<gridL, 256, 0, stream>>>(
        buf0, rpA2, edA, rpH2, edH,
        W + (size_t)4 * E * E, bias + 2 * E, users, items, out);
}